// Round 2
// baseline (251.441 us; speedup 1.0000x reference)
//
#include <hip/hip_runtime.h>
#include <cstdint>

// WeightedPolynormerGlobal: B=8, NMAX=8192, D=256, H=8, DH=32, rows N=65536.
// Pipeline: prep -> LN1 -> fused GEMM (h|q|k|v, N=1024) -> kv/ksum reduce ->
//           per-row attn+LN2 -> out GEMM (+relu+bias+residual).
// R1: GEMMs get LDS double-buffer (2-phase schedule, one barrier/K-step) and
//     XCD-aware block swizzle (A-panel L2 locality).

#define DEVI __device__ __forceinline__

typedef __attribute__((ext_vector_type(8))) short bf16x8;   // 8 bf16 in 4 VGPRs
typedef __attribute__((ext_vector_type(4))) float f32x4;

DEVI ushort f2bf(float f) {  // RNE float->bf16
  uint32_t u = __float_as_uint(f);
  u += 0x7FFFu + ((u >> 16) & 1u);
  return (ushort)(u >> 16);
}
DEVI float bf2f(ushort h) { return __uint_as_float(((uint32_t)h) << 16); }

DEVI void gload_lds16(const void* g, void* l) {
  __builtin_amdgcn_global_load_lds((const __attribute__((address_space(1))) void*)g,
                                   (__attribute__((address_space(3))) void*)l, 16, 0, 0);
}

// ---------------- K0: weight prep (transpose + bf16) + zero accumulators ----
__global__ __launch_bounds__(256)
void prep_k(const float* __restrict__ Wh, const float* __restrict__ Wq,
            const float* __restrict__ Wk, const float* __restrict__ Wv,
            const float* __restrict__ Wout,
            const float* __restrict__ bh, const float* __restrict__ bq,
            const float* __restrict__ bk, const float* __restrict__ bv,
            ushort* __restrict__ Wcat_t, ushort* __restrict__ Woutt,
            float* __restrict__ bcat, float* __restrict__ kv, float* __restrict__ ksum)
{
  int idx = blockIdx.x * 256 + threadIdx.x;
  if (idx < 262144) {                       // Wcat_t[j][kk] = W_g[kk][jj]
    int j = idx >> 8, kk = idx & 255;
    int g = j >> 8, jj = j & 255;
    const float* W = (g == 0) ? Wh : (g == 1) ? Wq : (g == 2) ? Wk : Wv;
    Wcat_t[idx] = f2bf(W[kk * 256 + jj]);
  }
  int i2 = idx - 262144;
  if (i2 >= 0 && i2 < 65536) {              // Woutt[j][kk] = Wout[kk][j]
    int j = i2 >> 8, kk = i2 & 255;
    Woutt[i2] = f2bf(Wout[kk * 256 + j]);
  }
  int i3 = idx - (262144 + 65536);
  if (i3 >= 0 && i3 < 1024) {
    int g = i3 >> 8, jj = i3 & 255;
    const float* bb = (g == 0) ? bh : (g == 1) ? bq : (g == 2) ? bk : bv;
    bcat[i3] = bb[jj];
  }
  int i4 = idx - (262144 + 65536 + 1024);
  if (i4 >= 0 && i4 < 65536) kv[i4] = 0.0f;
  int i5 = idx - (262144 + 65536 + 1024 + 65536);
  if (i5 >= 0 && i5 < 2048) ksum[i5] = 0.0f;
}

// ---------------- K1: LayerNorm1 -> x0 (bf16) --------------------------------
__global__ __launch_bounds__(256)
void ln1_k(const float* __restrict__ x, const float* __restrict__ g1,
           const float* __restrict__ b1, ushort* __restrict__ x0b)
{
  const int t = threadIdx.x, l = t & 63, w = t >> 6;
  const size_t r = (size_t)blockIdx.x * 4 + w;      // one row per wave
  const float4 xv = *(const float4*)&x[r * 256 + l * 4];
  float s = xv.x + xv.y + xv.z + xv.w;
  float sq = xv.x * xv.x + xv.y * xv.y + xv.z * xv.z + xv.w * xv.w;
#pragma unroll
  for (int off = 1; off < 64; off <<= 1) { s += __shfl_xor(s, off); sq += __shfl_xor(sq, off); }
  const float mean = s * (1.0f / 256.0f);
  const float var = sq * (1.0f / 256.0f) - mean * mean;
  const float rstd = rsqrtf(var + 1e-5f);
  const float4 g4 = *(const float4*)&g1[l * 4];
  const float4 b4 = *(const float4*)&b1[l * 4];
  ushort4 o;
  o.x = f2bf((xv.x - mean) * rstd * g4.x + b4.x);
  o.y = f2bf((xv.y - mean) * rstd * g4.y + b4.y);
  o.z = f2bf((xv.z - mean) * rstd * g4.z + b4.z);
  o.w = f2bf((xv.w - mean) * rstd * g4.w + b4.w);
  *(ushort4*)&x0b[r * 256 + l * 4] = o;
}

// ---------------- K2/K4b: bf16 MFMA GEMM, 128x128 tile, K=256, dbuf ----------
// MODE 0: A=x0b, Bt=Wcat_t (N=1024). epilogue: +bias; sigmoid for q,k; k*=node_prob -> bf16 hqkv
// MODE 1: A=z,   Bt=Woutt  (N=256).  epilogue: relu(+bout) + x0 residual -> f32 out
template <int MODE>
__global__ __launch_bounds__(256, 2)
void gemm_bf16_k(const ushort* __restrict__ A, const ushort* __restrict__ Bt,
                 const float* __restrict__ bias, const float* __restrict__ node_prob,
                 const ushort* __restrict__ x0b, ushort* __restrict__ outb,
                 float* __restrict__ outf)
{
  __shared__ ushort As[2][128 * 64];
  __shared__ ushort Bs[2][128 * 64];
  const int t = threadIdx.x;
  const int l = t & 63;
  const int w = t >> 6;
  const int wr = w >> 1, wc = w & 1;          // 2x2 waves of 64x64
  // XCD-bijective swizzle: grid %8==0; XCD x owns tiles [x*per, (x+1)*per)
  const int nNB = (MODE == 0) ? 8 : 2;
  const int per = gridDim.x >> 3;
  const int tile = (blockIdx.x & 7) * per + (blockIdx.x >> 3);
  const int m0 = (tile / nNB) * 128, n0 = (tile % nNB) * 128;
  const int lr = t >> 3;                       // staging: row-in-32-group
  const int ls = t & 7;                        // staging: 16B segment
  f32x4 acc[4][4] = {};

  auto stage = [&](int buf, int kt) {
#pragma unroll
    for (int i = 0; i < 4; ++i) {
      int row = i * 32 + lr;
      gload_lds16(&A[(size_t)(m0 + row) * 256 + kt * 64 + ls * 8], &As[buf][row * 64 + ls * 8]);
    }
#pragma unroll
    for (int i = 0; i < 4; ++i) {
      int row = i * 32 + lr;
      gload_lds16(&Bt[(size_t)(n0 + row) * 256 + kt * 64 + ls * 8], &Bs[buf][row * 64 + ls * 8]);
    }
  };

  stage(0, 0);
  __syncthreads();                              // vmcnt(0) drain + barrier: buf0 ready
#pragma unroll
  for (int kt = 0; kt < 4; ++kt) {
    const int cur = kt & 1;
    if (kt < 3) stage(cur ^ 1, kt + 1);         // prefetch next tile (latency hides under MFMA)
#pragma unroll
    for (int kk = 0; kk < 2; ++kk) {
      bf16x8 af[4], bfr[4];
#pragma unroll
      for (int f = 0; f < 4; ++f) {
        af[f]  = *(const bf16x8*)&As[cur][(wr * 64 + f * 16 + (l & 15)) * 64 + kk * 32 + (l >> 4) * 8];
        bfr[f] = *(const bf16x8*)&Bs[cur][(wc * 64 + f * 16 + (l & 15)) * 64 + kk * 32 + (l >> 4) * 8];
      }
#pragma unroll
      for (int fm = 0; fm < 4; ++fm)
#pragma unroll
        for (int fn = 0; fn < 4; ++fn)
          acc[fm][fn] = __builtin_amdgcn_mfma_f32_16x16x32_bf16(af[fm], bfr[fn], acc[fm][fn], 0, 0, 0);
    }
    __syncthreads();                            // reads done + staged buf ready
  }

  // epilogue: C row = (l>>4)*4+i, col = l&15 within each 16x16 fragment
#pragma unroll
  for (int fm = 0; fm < 4; ++fm) {
#pragma unroll
    for (int fn = 0; fn < 4; ++fn) {
#pragma unroll
      for (int i = 0; i < 4; ++i) {
        int r = m0 + wr * 64 + fm * 16 + (l >> 4) * 4 + i;
        int j = n0 + wc * 64 + fn * 16 + (l & 15);
        float v = acc[fm][fn][i] + bias[j];
        if (MODE == 0) {
          int g = j >> 8;                       // block-uniform (n0 is 128-aligned)
          if (g == 1 || g == 2) v = 1.0f / (1.0f + __expf(-v));
          if (g == 2) v *= node_prob[r];
          outb[(size_t)r * 1024 + j] = f2bf(v);
        } else {
          v = fmaxf(v, 0.0f);
          v += bf2f(x0b[(size_t)r * 256 + j]);
          outf[(size_t)r * 256 + j] = v;
        }
      }
    }
  }
}

// ---------------- K3: kv[b,h,d,e] = sum_n k*v ; ksum[b,h,d] = sum_n k --------
__global__ __launch_bounds__(256)
void kvred_k(const ushort* __restrict__ hqkv, float* __restrict__ kv, float* __restrict__ ksum)
{
  __shared__ ushort kt[64 * 32];
  __shared__ ushort vt[64 * 32];
  const int bh = blockIdx.x >> 5, chunk = blockIdx.x & 31;
  const int b = bh >> 3, h = bh & 7;
  const int t = threadIdx.x;
  const int d = t >> 3, e0 = (t & 7) * 4;      // thread owns (d, e0..e0+3)
  const int lrow = t >> 2, lseg = t & 3;
  float a0 = 0, a1 = 0, a2 = 0, a3 = 0, ks = 0;
  const size_t base = (size_t)b * 8192 + chunk * 256;
  for (int sub = 0; sub < 4; ++sub) {
    size_t grow = (base + sub * 64 + lrow) * 1024;
    gload_lds16(&hqkv[grow + 512 + h * 32 + lseg * 8], &kt[lrow * 32 + lseg * 8]);
    gload_lds16(&hqkv[grow + 768 + h * 32 + lseg * 8], &vt[lrow * 32 + lseg * 8]);
    __syncthreads();
#pragma unroll 8
    for (int nn = 0; nn < 64; ++nn) {
      float kd = bf2f(kt[nn * 32 + d]);
      ushort4 vv = *(const ushort4*)&vt[nn * 32 + e0];
      a0 += kd * bf2f(vv.x);
      a1 += kd * bf2f(vv.y);
      a2 += kd * bf2f(vv.z);
      a3 += kd * bf2f(vv.w);
      ks += kd;
    }
    __syncthreads();
  }
  float* kvp = &kv[(size_t)bh * 1024 + d * 32 + e0];
  atomicAdd(kvp + 0, a0);
  atomicAdd(kvp + 1, a1);
  atomicAdd(kvp + 2, a2);
  atomicAdd(kvp + 3, a3);
  if ((t & 7) == 0) atomicAdd(&ksum[bh * 32 + d], ks);
}

// ---------------- K4a: att=num/den, LN2, z = LN2(att)*(h+beta) ---------------
__global__ __launch_bounds__(256)
void attnz_k(const ushort* __restrict__ hqkv, const float* __restrict__ kv,
             const float* __restrict__ ksum, const float* __restrict__ g2,
             const float* __restrict__ b2, const float* __restrict__ beta,
             ushort* __restrict__ zb)
{
  __shared__ float kv_s[8192];                 // kv[b] : [h][d][e]
  __shared__ float ks_s[256];                  // ksum[b] : [h][d]
  __shared__ float q_s[16][256];               // q rows of this block
  const int t = threadIdx.x, l = t & 63, w = t >> 6;
  const int r0 = blockIdx.x * 16;              // 16 rows/block, all in one b
  const int b = r0 >> 13;
#pragma unroll
  for (int i = 0; i < 8; ++i)
    *(float4*)&kv_s[i * 1024 + t * 4] = *(const float4*)&kv[(size_t)b * 8192 + i * 1024 + t * 4];
  if (t < 64) *(float4*)&ks_s[t * 4] = *(const float4*)&ksum[b * 256 + t * 4];
#pragma unroll
  for (int rr = 0; rr < 4; ++rr) {             // wave w owns rows r0+w*4 .. +3
    int r = r0 + w * 4 + rr;
    ushort4 qv = *(const ushort4*)&hqkv[(size_t)r * 1024 + 256 + l * 4];
    float4 qf = {bf2f(qv.x), bf2f(qv.y), bf2f(qv.z), bf2f(qv.w)};
    *(float4*)&q_s[w * 4 + rr][l * 4] = qf;
  }
  __syncthreads();

  const int h = l >> 3, e0 = (l & 7) * 4;      // lane owns outputs j=l*4..l*4+3
  float num[4][4] = {};
  float den[4] = {0.0f, 0.0f, 0.0f, 0.0f};
#pragma unroll
  for (int dl = 0; dl < 8; ++dl) {
    const float4 ks4 = *(const float4*)&ks_s[h * 32 + dl * 4];
    float4 kvv[4];
#pragma unroll
    for (int c = 0; c < 4; ++c)
      kvv[c] = *(const float4*)&kv_s[h * 1024 + (dl * 4 + c) * 32 + e0];
#pragma unroll
    for (int rr = 0; rr < 4; ++rr) {
      const float4 q4 = *(const float4*)&q_s[w * 4 + rr][h * 32 + dl * 4];
      den[rr] += q4.x * ks4.x + q4.y * ks4.y + q4.z * ks4.z + q4.w * ks4.w;
      num[rr][0] += q4.x * kvv[0].x + q4.y * kvv[1].x + q4.z * kvv[2].x + q4.w * kvv[3].x;
      num[rr][1] += q4.x * kvv[0].y + q4.y * kvv[1].y + q4.z * kvv[2].y + q4.w * kvv[3].y;
      num[rr][2] += q4.x * kvv[0].z + q4.y * kvv[1].z + q4.z * kvv[2].z + q4.w * kvv[3].z;
      num[rr][3] += q4.x * kvv[0].w + q4.y * kvv[1].w + q4.z * kvv[2].w + q4.w * kvv[3].w;
    }
  }
  const float4 g4 = *(const float4*)&g2[l * 4];
  const float4 bb4 = *(const float4*)&b2[l * 4];
  const float4 be4 = *(const float4*)&beta[l * 4];
#pragma unroll
  for (int rr = 0; rr < 4; ++rr) {
    const int r = r0 + w * 4 + rr;
    const float inv = 1.0f / den[rr];
    float a0 = num[rr][0] * inv, a1 = num[rr][1] * inv;
    float a2 = num[rr][2] * inv, a3 = num[rr][3] * inv;
    float s = a0 + a1 + a2 + a3;
    float sq = a0 * a0 + a1 * a1 + a2 * a2 + a3 * a3;
#pragma unroll
    for (int off = 1; off < 64; off <<= 1) { s += __shfl_xor(s, off); sq += __shfl_xor(sq, off); }
    const float mean = s * (1.0f / 256.0f);
    const float var = sq * (1.0f / 256.0f) - mean * mean;
    const float rstd = rsqrtf(var + 1e-5f);
    ushort4 hv = *(const ushort4*)&hqkv[(size_t)r * 1024 + l * 4];
    ushort4 o;
    o.x = f2bf(((a0 - mean) * rstd * g4.x + bb4.x) * (bf2f(hv.x) + be4.x));
    o.y = f2bf(((a1 - mean) * rstd * g4.y + bb4.y) * (bf2f(hv.y) + be4.y));
    o.z = f2bf(((a2 - mean) * rstd * g4.z + bb4.z) * (bf2f(hv.z) + be4.z));
    o.w = f2bf(((a3 - mean) * rstd * g4.w + bb4.w) * (bf2f(hv.w) + be4.w));
    *(ushort4*)&zb[(size_t)r * 256 + l * 4] = o;
  }
}

// ---------------- host: launch -----------------------------------------------
extern "C" void kernel_launch(void* const* d_in, const int* in_sizes, int n_in,
                              void* d_out, int out_size, void* d_ws, size_t ws_size,
                              hipStream_t stream)
{
  const float* x    = (const float*)d_in[0];
  const float* np_  = (const float*)d_in[1];
  const float* Wh   = (const float*)d_in[2];
  const float* bh   = (const float*)d_in[3];
  const float* Wq   = (const float*)d_in[4];
  const float* bq   = (const float*)d_in[5];
  const float* Wk   = (const float*)d_in[6];
  const float* bk   = (const float*)d_in[7];
  const float* Wv   = (const float*)d_in[8];
  const float* bv   = (const float*)d_in[9];
  const float* Wout = (const float*)d_in[10];
  const float* bout = (const float*)d_in[11];
  const float* ln1g = (const float*)d_in[12];
  const float* ln1b = (const float*)d_in[13];
  const float* ln2g = (const float*)d_in[14];
  const float* ln2b = (const float*)d_in[15];
  const float* beta = (const float*)d_in[16];
  float* out = (float*)d_out;

  // workspace carve (~202 MB)
  uintptr_t p = (uintptr_t)d_ws;
  ushort* x0b    = (ushort*)p; p += (size_t)65536 * 256 * 2;   // 33.5 MB
  ushort* hqkv   = (ushort*)p; p += (size_t)65536 * 1024 * 2;  // 134 MB
  ushort* zb     = (ushort*)p; p += (size_t)65536 * 256 * 2;   // 33.5 MB
  ushort* Wcat_t = (ushort*)p; p += (size_t)1024 * 256 * 2;
  ushort* Woutt  = (ushort*)p; p += (size_t)256 * 256 * 2;
  float*  bcat   = (float*)p;  p += (size_t)1024 * 4;
  float*  kv     = (float*)p;  p += (size_t)65536 * 4;
  float*  ksum   = (float*)p;  p += (size_t)2048 * 4;

  prep_k<<<1548, 256, 0, stream>>>(Wh, Wq, Wk, Wv, Wout, bh, bq, bk, bv,
                                   Wcat_t, Woutt, bcat, kv, ksum);
  ln1_k<<<16384, 256, 0, stream>>>(x, ln1g, ln1b, x0b);
  gemm_bf16_k<0><<<4096, 256, 0, stream>>>(x0b, Wcat_t, bcat, np_, nullptr, hqkv, nullptr);
  kvred_k<<<2048, 256, 0, stream>>>(hqkv, kv, ksum);
  attnz_k<<<4096, 256, 0, stream>>>(hqkv, kv, ksum, ln2g, ln2b, beta, zb);
  gemm_bf16_k<1><<<1024, 256, 0, stream>>>(zb, Woutt, bout, nullptr, x0b, nullptr, out);
}

// Round 4
// 238.105 us; speedup vs baseline: 1.0560x; 1.0560x over previous
//
#include <hip/hip_runtime.h>
#include <cstdint>

// WeightedPolynormerGlobal: B=8, NMAX=8192, D=256, H=8, DH=32, rows N=65536.
// Pipeline: prep -> LN1 -> fused GEMM (h|q|k|v, N=1024) -> kv/ksum reduce ->
//           per-row attn+LN2 -> out GEMM (+relu+bias+residual).
// R1: dbuf + XCD swizzle (FETCH 132->19MB).
// R2: T2 XOR bank-swizzle on LDS tiles (pre-swizzled global src + swizzled read).
// R3: FIX race — explicit s_waitcnt vmcnt(0) before every barrier that
//     publishes global_load_lds data (LDS-DMA is vmcnt-tracked; the compiler's
//     workgroup fence does not reliably drain it). R2's faster consume path
//     exposed the latent hazard as post-timing divergence.

#define DEVI __device__ __forceinline__

typedef __attribute__((ext_vector_type(8))) short bf16x8;   // 8 bf16 in 4 VGPRs
typedef __attribute__((ext_vector_type(4))) float f32x4;

DEVI ushort f2bf(float f) {  // RNE float->bf16
  uint32_t u = __float_as_uint(f);
  u += 0x7FFFu + ((u >> 16) & 1u);
  return (ushort)(u >> 16);
}
DEVI float bf2f(ushort h) { return __uint_as_float(((uint32_t)h) << 16); }

DEVI void gload_lds16(const void* g, void* l) {
  __builtin_amdgcn_global_load_lds((const __attribute__((address_space(1))) void*)g,
                                   (__attribute__((address_space(3))) void*)l, 16, 0, 0);
}
DEVI void vm_drain() { asm volatile("s_waitcnt vmcnt(0)" ::: "memory"); }

// ---------------- K0: weight prep (transpose + bf16) + zero accumulators ----
__global__ __launch_bounds__(256)
void prep_k(const float* __restrict__ Wh, const float* __restrict__ Wq,
            const float* __restrict__ Wk, const float* __restrict__ Wv,
            const float* __restrict__ Wout,
            const float* __restrict__ bh, const float* __restrict__ bq,
            const float* __restrict__ bk, const float* __restrict__ bv,
            ushort* __restrict__ Wcat_t, ushort* __restrict__ Woutt,
            float* __restrict__ bcat, float* __restrict__ kv, float* __restrict__ ksum)
{
  int idx = blockIdx.x * 256 + threadIdx.x;
  if (idx < 262144) {                       // Wcat_t[j][kk] = W_g[kk][jj]
    int j = idx >> 8, kk = idx & 255;
    int g = j >> 8, jj = j & 255;
    const float* W = (g == 0) ? Wh : (g == 1) ? Wq : (g == 2) ? Wk : Wv;
    Wcat_t[idx] = f2bf(W[kk * 256 + jj]);
  }
  int i2 = idx - 262144;
  if (i2 >= 0 && i2 < 65536) {              // Woutt[j][kk] = Wout[kk][j]
    int j = i2 >> 8, kk = i2 & 255;
    Woutt[i2] = f2bf(Wout[kk * 256 + j]);
  }
  int i3 = idx - (262144 + 65536);
  if (i3 >= 0 && i3 < 1024) {
    int g = i3 >> 8, jj = i3 & 255;
    const float* bb = (g == 0) ? bh : (g == 1) ? bq : (g == 2) ? bk : bv;
    bcat[i3] = bb[jj];
  }
  int i4 = idx - (262144 + 65536 + 1024);
  if (i4 >= 0 && i4 < 65536) kv[i4] = 0.0f;
  int i5 = idx - (262144 + 65536 + 1024 + 65536);
  if (i5 >= 0 && i5 < 2048) ksum[i5] = 0.0f;
}

// ---------------- K1: LayerNorm1 -> x0 (bf16) --------------------------------
__global__ __launch_bounds__(256)
void ln1_k(const float* __restrict__ x, const float* __restrict__ g1,
           const float* __restrict__ b1, ushort* __restrict__ x0b)
{
  const int t = threadIdx.x, l = t & 63, w = t >> 6;
  const size_t r = (size_t)blockIdx.x * 4 + w;      // one row per wave
  const float4 xv = *(const float4*)&x[r * 256 + l * 4];
  float s = xv.x + xv.y + xv.z + xv.w;
  float sq = xv.x * xv.x + xv.y * xv.y + xv.z * xv.z + xv.w * xv.w;
#pragma unroll
  for (int off = 1; off < 64; off <<= 1) { s += __shfl_xor(s, off); sq += __shfl_xor(sq, off); }
  const float mean = s * (1.0f / 256.0f);
  const float var = sq * (1.0f / 256.0f) - mean * mean;
  const float rstd = rsqrtf(var + 1e-5f);
  const float4 g4 = *(const float4*)&g1[l * 4];
  const float4 b4 = *(const float4*)&b1[l * 4];
  ushort4 o;
  o.x = f2bf((xv.x - mean) * rstd * g4.x + b4.x);
  o.y = f2bf((xv.y - mean) * rstd * g4.y + b4.y);
  o.z = f2bf((xv.z - mean) * rstd * g4.z + b4.z);
  o.w = f2bf((xv.w - mean) * rstd * g4.w + b4.w);
  *(ushort4*)&x0b[r * 256 + l * 4] = o;
}

// ---------------- K2/K4b: bf16 MFMA GEMM, 128x128 tile, K=256, dbuf, swz -----
// LDS tile [128 rows][8 slots of 16B]; LDS slot s holds global slot s^(row&7).
// MODE 0: A=x0b, Bt=Wcat_t (N=1024). epilogue: +bias; sigmoid q,k; k*=node_prob -> bf16 hqkv
// MODE 1: A=z,   Bt=Woutt  (N=256).  epilogue: relu(+bout) + x0 residual -> f32 out
template <int MODE>
__global__ __launch_bounds__(256, 2)
void gemm_bf16_k(const ushort* __restrict__ A, const ushort* __restrict__ Bt,
                 const float* __restrict__ bias, const float* __restrict__ node_prob,
                 const ushort* __restrict__ x0b, ushort* __restrict__ outb,
                 float* __restrict__ outf)
{
  __shared__ ushort As[2][128 * 64];
  __shared__ ushort Bs[2][128 * 64];
  const int t = threadIdx.x;
  const int l = t & 63;
  const int w = t >> 6;
  const int wr = w >> 1, wc = w & 1;          // 2x2 waves of 64x64
  // XCD-bijective swizzle: grid %8==0; XCD x owns tiles [x*per, (x+1)*per)
  const int nNB = (MODE == 0) ? 8 : 2;
  const int per = gridDim.x >> 3;
  const int tile = (blockIdx.x & 7) * per + (blockIdx.x >> 3);
  const int m0 = (tile / nNB) * 128, n0 = (tile % nNB) * 128;
  const int lr = t >> 3;                       // staging: row-in-32-group
  const int ls = t & 7;                        // staging: 16B dest slot (linear)
  const int ss = ls ^ (lr & 7);                // staging: pre-swizzled SRC slot
  f32x4 acc[4][4] = {};

  auto stage = [&](int buf, int kt) {
#pragma unroll
    for (int i = 0; i < 4; ++i) {
      int row = i * 32 + lr;                   // row&7 == lr&7
      gload_lds16(&A[(size_t)(m0 + row) * 256 + kt * 64 + ss * 8], &As[buf][row * 64 + ls * 8]);
    }
#pragma unroll
    for (int i = 0; i < 4; ++i) {
      int row = i * 32 + lr;
      gload_lds16(&Bt[(size_t)(n0 + row) * 256 + kt * 64 + ss * 8], &Bs[buf][row * 64 + ls * 8]);
    }
  };

  stage(0, 0);
  vm_drain();                                   // LDS-DMA is vmcnt-tracked: drain before publish
  __syncthreads();                              // buf0 ready
#pragma unroll
  for (int kt = 0; kt < 4; ++kt) {
    const int cur = kt & 1;
    if (kt < 3) stage(cur ^ 1, kt + 1);         // prefetch next tile under MFMA
#pragma unroll
    for (int kk = 0; kk < 2; ++kk) {
      const int rsl = ((kk * 4 + (l >> 4)) ^ (l & 7)) * 8;  // swizzled read slot (ushorts)
      bf16x8 af[4], bfr[4];
#pragma unroll
      for (int f = 0; f < 4; ++f) {
        // row&7 == l&7 for both A and B fragment rows (wr*64, wc*64, f*16 all %8==0)
        af[f]  = *(const bf16x8*)&As[cur][(wr * 64 + f * 16 + (l & 15)) * 64 + rsl];
        bfr[f] = *(const bf16x8*)&Bs[cur][(wc * 64 + f * 16 + (l & 15)) * 64 + rsl];
      }
#pragma unroll
      for (int fm = 0; fm < 4; ++fm)
#pragma unroll
        for (int fn = 0; fn < 4; ++fn)
          acc[fm][fn] = __builtin_amdgcn_mfma_f32_16x16x32_bf16(af[fm], bfr[fn], acc[fm][fn], 0, 0, 0);
    }
    vm_drain();                                 // staged buf's DMA complete before publish
    __syncthreads();                            // reads done + staged buf ready
  }

  // epilogue: C row = (l>>4)*4+i, col = l&15 within each 16x16 fragment
#pragma unroll
  for (int fm = 0; fm < 4; ++fm) {
#pragma unroll
    for (int fn = 0; fn < 4; ++fn) {
#pragma unroll
      for (int i = 0; i < 4; ++i) {
        int r = m0 + wr * 64 + fm * 16 + (l >> 4) * 4 + i;
        int j = n0 + wc * 64 + fn * 16 + (l & 15);
        float v = acc[fm][fn][i] + bias[j];
        if (MODE == 0) {
          int g = j >> 8;                       // block-uniform (n0 is 128-aligned)
          if (g == 1 || g == 2) v = 1.0f / (1.0f + __expf(-v));
          if (g == 2) v *= node_prob[r];
          outb[(size_t)r * 1024 + j] = f2bf(v);
        } else {
          v = fmaxf(v, 0.0f);
          v += bf2f(x0b[(size_t)r * 256 + j]);
          outf[(size_t)r * 256 + j] = v;
        }
      }
    }
  }
}

// ---------------- K3: kv[b,h,d,e] = sum_n k*v ; ksum[b,h,d] = sum_n k --------
__global__ __launch_bounds__(256)
void kvred_k(const ushort* __restrict__ hqkv, float* __restrict__ kv, float* __restrict__ ksum)
{
  __shared__ ushort kt[64 * 32];
  __shared__ ushort vt[64 * 32];
  const int bh = blockIdx.x >> 5, chunk = blockIdx.x & 31;
  const int b = bh >> 3, h = bh & 7;
  const int t = threadIdx.x;
  const int d = t >> 3, e0 = (t & 7) * 4;      // thread owns (d, e0..e0+3)
  const int lrow = t >> 2, lseg = t & 3;
  float a0 = 0, a1 = 0, a2 = 0, a3 = 0, ks = 0;
  const size_t base = (size_t)b * 8192 + chunk * 256;
  for (int sub = 0; sub < 4; ++sub) {
    size_t grow = (base + sub * 64 + lrow) * 1024;
    gload_lds16(&hqkv[grow + 512 + h * 32 + lseg * 8], &kt[lrow * 32 + lseg * 8]);
    gload_lds16(&hqkv[grow + 768 + h * 32 + lseg * 8], &vt[lrow * 32 + lseg * 8]);
    vm_drain();                                 // LDS-DMA complete before publish
    __syncthreads();
#pragma unroll 8
    for (int nn = 0; nn < 64; ++nn) {
      float kd = bf2f(kt[nn * 32 + d]);
      ushort4 vv = *(const ushort4*)&vt[nn * 32 + e0];
      a0 += kd * bf2f(vv.x);
      a1 += kd * bf2f(vv.y);
      a2 += kd * bf2f(vv.z);
      a3 += kd * bf2f(vv.w);
      ks += kd;
    }
    __syncthreads();
  }
  float* kvp = &kv[(size_t)bh * 1024 + d * 32 + e0];
  atomicAdd(kvp + 0, a0);
  atomicAdd(kvp + 1, a1);
  atomicAdd(kvp + 2, a2);
  atomicAdd(kvp + 3, a3);
  if ((t & 7) == 0) atomicAdd(&ksum[bh * 32 + d], ks);
}

// ---------------- K4a: att=num/den, LN2, z = LN2(att)*(h+beta) ---------------
__global__ __launch_bounds__(256)
void attnz_k(const ushort* __restrict__ hqkv, const float* __restrict__ kv,
             const float* __restrict__ ksum, const float* __restrict__ g2,
             const float* __restrict__ b2, const float* __restrict__ beta,
             ushort* __restrict__ zb)
{
  __shared__ float kv_s[8192];                 // kv[b] : [h][d][e]
  __shared__ float ks_s[256];                  // ksum[b] : [h][d]
  __shared__ float q_s[16][256];               // q rows of this block
  const int t = threadIdx.x, l = t & 63, w = t >> 6;
  const int r0 = blockIdx.x * 16;              // 16 rows/block, all in one b
  const int b = r0 >> 13;
#pragma unroll
  for (int i = 0; i < 8; ++i)
    *(float4*)&kv_s[i * 1024 + t * 4] = *(const float4*)&kv[(size_t)b * 8192 + i * 1024 + t * 4];
  if (t < 64) *(float4*)&ks_s[t * 4] = *(const float4*)&ksum[b * 256 + t * 4];
#pragma unroll
  for (int rr = 0; rr < 4; ++rr) {             // wave w owns rows r0+w*4 .. +3
    int r = r0 + w * 4 + rr;
    ushort4 qv = *(const ushort4*)&hqkv[(size_t)r * 1024 + 256 + l * 4];
    float4 qf = {bf2f(qv.x), bf2f(qv.y), bf2f(qv.z), bf2f(qv.w)};
    *(float4*)&q_s[w * 4 + rr][l * 4] = qf;
  }
  __syncthreads();

  const int h = l >> 3, e0 = (l & 7) * 4;      // lane owns outputs j=l*4..l*4+3
  float num[4][4] = {};
  float den[4] = {0.0f, 0.0f, 0.0f, 0.0f};
#pragma unroll
  for (int dl = 0; dl < 8; ++dl) {
    const float4 ks4 = *(const float4*)&ks_s[h * 32 + dl * 4];
    float4 kvv[4];
#pragma unroll
    for (int c = 0; c < 4; ++c)
      kvv[c] = *(const float4*)&kv_s[h * 1024 + (dl * 4 + c) * 32 + e0];
#pragma unroll
    for (int rr = 0; rr < 4; ++rr) {
      const float4 q4 = *(const float4*)&q_s[w * 4 + rr][h * 32 + dl * 4];
      den[rr] += q4.x * ks4.x + q4.y * ks4.y + q4.z * ks4.z + q4.w * ks4.w;
      num[rr][0] += q4.x * kvv[0].x + q4.y * kvv[1].x + q4.z * kvv[2].x + q4.w * kvv[3].x;
      num[rr][1] += q4.x * kvv[0].y + q4.y * kvv[1].y + q4.z * kvv[2].y + q4.w * kvv[3].y;
      num[rr][2] += q4.x * kvv[0].z + q4.y * kvv[1].z + q4.z * kvv[2].z + q4.w * kvv[3].z;
      num[rr][3] += q4.x * kvv[0].w + q4.y * kvv[1].w + q4.z * kvv[2].w + q4.w * kvv[3].w;
    }
  }
  const float4 g4 = *(const float4*)&g2[l * 4];
  const float4 bb4 = *(const float4*)&b2[l * 4];
  const float4 be4 = *(const float4*)&beta[l * 4];
#pragma unroll
  for (int rr = 0; rr < 4; ++rr) {
    const int r = r0 + w * 4 + rr;
    const float inv = 1.0f / den[rr];
    float a0 = num[rr][0] * inv, a1 = num[rr][1] * inv;
    float a2 = num[rr][2] * inv, a3 = num[rr][3] * inv;
    float s = a0 + a1 + a2 + a3;
    float sq = a0 * a0 + a1 * a1 + a2 * a2 + a3 * a3;
#pragma unroll
    for (int off = 1; off < 64; off <<= 1) { s += __shfl_xor(s, off); sq += __shfl_xor(sq, off); }
    const float mean = s * (1.0f / 256.0f);
    const float var = sq * (1.0f / 256.0f) - mean * mean;
    const float rstd = rsqrtf(var + 1e-5f);
    ushort4 hv = *(const ushort4*)&hqkv[(size_t)r * 1024 + l * 4];
    ushort4 o;
    o.x = f2bf(((a0 - mean) * rstd * g4.x + bb4.x) * (bf2f(hv.x) + be4.x));
    o.y = f2bf(((a1 - mean) * rstd * g4.y + bb4.y) * (bf2f(hv.y) + be4.y));
    o.z = f2bf(((a2 - mean) * rstd * g4.z + bb4.z) * (bf2f(hv.z) + be4.z));
    o.w = f2bf(((a3 - mean) * rstd * g4.w + bb4.w) * (bf2f(hv.w) + be4.w));
    *(ushort4*)&zb[(size_t)r * 256 + l * 4] = o;
  }
}

// ---------------- host: launch -----------------------------------------------
extern "C" void kernel_launch(void* const* d_in, const int* in_sizes, int n_in,
                              void* d_out, int out_size, void* d_ws, size_t ws_size,
                              hipStream_t stream)
{
  const float* x    = (const float*)d_in[0];
  const float* np_  = (const float*)d_in[1];
  const float* Wh   = (const float*)d_in[2];
  const float* bh   = (const float*)d_in[3];
  const float* Wq   = (const float*)d_in[4];
  const float* bq   = (const float*)d_in[5];
  const float* Wk   = (const float*)d_in[6];
  const float* bk   = (const float*)d_in[7];
  const float* Wv   = (const float*)d_in[8];
  const float* bv   = (const float*)d_in[9];
  const float* Wout = (const float*)d_in[10];
  const float* bout = (const float*)d_in[11];
  const float* ln1g = (const float*)d_in[12];
  const float* ln1b = (const float*)d_in[13];
  const float* ln2g = (const float*)d_in[14];
  const float* ln2b = (const float*)d_in[15];
  const float* beta = (const float*)d_in[16];
  float* out = (float*)d_out;

  // workspace carve (~202 MB)
  uintptr_t p = (uintptr_t)d_ws;
  ushort* x0b    = (ushort*)p; p += (size_t)65536 * 256 * 2;   // 33.5 MB
  ushort* hqkv   = (ushort*)p; p += (size_t)65536 * 1024 * 2;  // 134 MB
  ushort* zb     = (ushort*)p; p += (size_t)65536 * 256 * 2;   // 33.5 MB
  ushort* Wcat_t = (ushort*)p; p += (size_t)1024 * 256 * 2;
  ushort* Woutt  = (ushort*)p; p += (size_t)256 * 256 * 2;
  float*  bcat   = (float*)p;  p += (size_t)1024 * 4;
  float*  kv     = (float*)p;  p += (size_t)65536 * 4;
  float*  ksum   = (float*)p;  p += (size_t)2048 * 4;

  prep_k<<<1548, 256, 0, stream>>>(Wh, Wq, Wk, Wv, Wout, bh, bq, bk, bv,
                                   Wcat_t, Woutt, bcat, kv, ksum);
  ln1_k<<<16384, 256, 0, stream>>>(x, ln1g, ln1b, x0b);
  gemm_bf16_k<0><<<4096, 256, 0, stream>>>(x0b, Wcat_t, bcat, np_, nullptr, hqkv, nullptr);
  kvred_k<<<2048, 256, 0, stream>>>(hqkv, kv, ksum);
  attnz_k<<<4096, 256, 0, stream>>>(hqkv, kv, ksum, ln2g, ln2b, beta, zb);
  gemm_bf16_k<1><<<1024, 256, 0, stream>>>(zb, Woutt, bout, nullptr, x0b, nullptr, out);
}

// Round 5
// 215.475 us; speedup vs baseline: 1.1669x; 1.1050x over previous
//
#include <hip/hip_runtime.h>
#include <cstdint>

// WeightedPolynormerGlobal: B=8, NMAX=8192, D=256, H=8, DH=32, rows N=65536.
// Pipeline: prep -> LN1 -> fused GEMM (h|q|k|v, N=1024) -> kv/ksum reduce ->
//           per-row attn+LN2 -> out GEMM (+relu+bias+residual).
// R1: dbuf + XCD swizzle (FETCH 132->19MB).
// R2: T2 XOR bank-swizzle (conflicts 1.26e7 -> 0).
// R3: vmcnt(0) drain before publishing global_load_lds data (race fix).
// R4 analysis: latency-bound, epilogue-heavy at K=256. This round:
//   - BK=32, LDS 32KB -> 4 blocks/CU (launch_bounds(256,4)) for 2x TLP
//   - LDS-staged coalesced epilogue (16B vector stores, hoisted bias)

#define DEVI __device__ __forceinline__

typedef __attribute__((ext_vector_type(8))) short bf16x8;   // 8 bf16 in 4 VGPRs
typedef __attribute__((ext_vector_type(4))) float f32x4;

DEVI ushort f2bf(float f) {  // RNE float->bf16
  uint32_t u = __float_as_uint(f);
  u += 0x7FFFu + ((u >> 16) & 1u);
  return (ushort)(u >> 16);
}
DEVI float bf2f(ushort h) { return __uint_as_float(((uint32_t)h) << 16); }

DEVI void gload_lds16(const void* g, void* l) {
  __builtin_amdgcn_global_load_lds((const __attribute__((address_space(1))) void*)g,
                                   (__attribute__((address_space(3))) void*)l, 16, 0, 0);
}
DEVI void vm_drain() { asm volatile("s_waitcnt vmcnt(0)" ::: "memory"); }

// ---------------- K0: weight prep (transpose + bf16) + zero accumulators ----
__global__ __launch_bounds__(256)
void prep_k(const float* __restrict__ Wh, const float* __restrict__ Wq,
            const float* __restrict__ Wk, const float* __restrict__ Wv,
            const float* __restrict__ Wout,
            const float* __restrict__ bh, const float* __restrict__ bq,
            const float* __restrict__ bk, const float* __restrict__ bv,
            ushort* __restrict__ Wcat_t, ushort* __restrict__ Woutt,
            float* __restrict__ bcat, float* __restrict__ kv, float* __restrict__ ksum)
{
  int idx = blockIdx.x * 256 + threadIdx.x;
  if (idx < 262144) {                       // Wcat_t[j][kk] = W_g[kk][jj]
    int j = idx >> 8, kk = idx & 255;
    int g = j >> 8, jj = j & 255;
    const float* W = (g == 0) ? Wh : (g == 1) ? Wq : (g == 2) ? Wk : Wv;
    Wcat_t[idx] = f2bf(W[kk * 256 + jj]);
  }
  int i2 = idx - 262144;
  if (i2 >= 0 && i2 < 65536) {              // Woutt[j][kk] = Wout[kk][j]
    int j = i2 >> 8, kk = i2 & 255;
    Woutt[i2] = f2bf(Wout[kk * 256 + j]);
  }
  int i3 = idx - (262144 + 65536);
  if (i3 >= 0 && i3 < 1024) {
    int g = i3 >> 8, jj = i3 & 255;
    const float* bb = (g == 0) ? bh : (g == 1) ? bq : (g == 2) ? bk : bv;
    bcat[i3] = bb[jj];
  }
  int i4 = idx - (262144 + 65536 + 1024);
  if (i4 >= 0 && i4 < 65536) kv[i4] = 0.0f;
  int i5 = idx - (262144 + 65536 + 1024 + 65536);
  if (i5 >= 0 && i5 < 2048) ksum[i5] = 0.0f;
}

// ---------------- K1: LayerNorm1 -> x0 (bf16) --------------------------------
__global__ __launch_bounds__(256)
void ln1_k(const float* __restrict__ x, const float* __restrict__ g1,
           const float* __restrict__ b1, ushort* __restrict__ x0b)
{
  const int t = threadIdx.x, l = t & 63, w = t >> 6;
  const size_t r = (size_t)blockIdx.x * 4 + w;      // one row per wave
  const float4 xv = *(const float4*)&x[r * 256 + l * 4];
  float s = xv.x + xv.y + xv.z + xv.w;
  float sq = xv.x * xv.x + xv.y * xv.y + xv.z * xv.z + xv.w * xv.w;
#pragma unroll
  for (int off = 1; off < 64; off <<= 1) { s += __shfl_xor(s, off); sq += __shfl_xor(sq, off); }
  const float mean = s * (1.0f / 256.0f);
  const float var = sq * (1.0f / 256.0f) - mean * mean;
  const float rstd = rsqrtf(var + 1e-5f);
  const float4 g4 = *(const float4*)&g1[l * 4];
  const float4 b4 = *(const float4*)&b1[l * 4];
  ushort4 o;
  o.x = f2bf((xv.x - mean) * rstd * g4.x + b4.x);
  o.y = f2bf((xv.y - mean) * rstd * g4.y + b4.y);
  o.z = f2bf((xv.z - mean) * rstd * g4.z + b4.z);
  o.w = f2bf((xv.w - mean) * rstd * g4.w + b4.w);
  *(ushort4*)&x0b[r * 256 + l * 4] = o;
}

// ---------------- K2/K4b: bf16 MFMA GEMM, 128x128 tile, BK=32, dbuf, swz -----
// LDS 32KB: As[2][128*32] | Bs[2][128*32]; reused as C-stage [128][128] bf16.
// Slot swizzle: LDS[row][s] holds global 16B-slot s ^ ((row>>1)&3).
// C-stage swizzle: 16-ushort blocks, col ^ ((row&7)<<4).
// MODE 0: A=x0b, Bt=Wcat_t (N=1024). epi: +bias; sigmoid q,k; k*=node_prob -> bf16 hqkv
// MODE 1: A=z,   Bt=Woutt  (N=256).  epi: relu(+bout), stage bf16, +x0 -> f32 out
template <int MODE>
__global__ __launch_bounds__(256, 4)
void gemm_bf16_k(const ushort* __restrict__ A, const ushort* __restrict__ Bt,
                 const float* __restrict__ bias, const float* __restrict__ node_prob,
                 const ushort* __restrict__ x0b, ushort* __restrict__ outb,
                 float* __restrict__ outf)
{
  __shared__ ushort smem[16384];               // 32 KB
  const int t = threadIdx.x;
  const int l = t & 63;
  const int w = t >> 6;
  const int wr = w >> 1, wc = w & 1;           // 2x2 waves of 64x64
  // XCD-bijective swizzle: grid %8==0; XCD x owns tiles [x*per, (x+1)*per)
  const int nNB = (MODE == 0) ? 8 : 2;
  const int per = gridDim.x >> 3;
  const int tile = (blockIdx.x & 7) * per + (blockIdx.x >> 3);
  const int m0 = (tile / nNB) * 128, n0 = (tile % nNB) * 128;
  // staging: thread t covers (row = i*64 + t>>2, dest slot t&3); linear lane*16B dest
  const int sr = t >> 2;
  const int sd = t & 3;
  const int ssl = sd ^ ((t >> 3) & 3);         // pre-swizzled global src slot
  f32x4 acc[4][4] = {};

  auto stage = [&](int buf, int kt) {
#pragma unroll
    for (int i = 0; i < 2; ++i) {
      int row = i * 64 + sr;
      gload_lds16(&A[(size_t)(m0 + row) * 256 + kt * 32 + ssl * 8],
                  &smem[buf * 4096 + row * 32 + sd * 8]);
    }
#pragma unroll
    for (int i = 0; i < 2; ++i) {
      int row = i * 64 + sr;
      gload_lds16(&Bt[(size_t)(n0 + row) * 256 + kt * 32 + ssl * 8],
                  &smem[8192 + buf * 4096 + row * 32 + sd * 8]);
    }
  };

  stage(0, 0);
  vm_drain();                                   // LDS-DMA is vmcnt-tracked
  __syncthreads();                              // buf0 ready
  const int fr = l & 15;                        // fragment row within 16
  const int fq = l >> 4;                        // K-group (16B slot)
  const int fsl = (fq ^ ((l >> 1) & 3)) * 8;    // swizzled slot (ushort offset)
#pragma unroll
  for (int kt = 0; kt < 8; ++kt) {
    const int cur = kt & 1;
    if (kt < 7) stage(cur ^ 1, kt + 1);         // prefetch next K-step
    bf16x8 af[4], bfr[4];
#pragma unroll
    for (int f = 0; f < 4; ++f) {
      af[f]  = *(const bf16x8*)&smem[cur * 4096 + (wr * 64 + f * 16 + fr) * 32 + fsl];
      bfr[f] = *(const bf16x8*)&smem[8192 + cur * 4096 + (wc * 64 + f * 16 + fr) * 32 + fsl];
    }
#pragma unroll
    for (int fm = 0; fm < 4; ++fm)
#pragma unroll
      for (int fn = 0; fn < 4; ++fn)
        acc[fm][fn] = __builtin_amdgcn_mfma_f32_16x16x32_bf16(af[fm], bfr[fn], acc[fm][fn], 0, 0, 0);
    vm_drain();                                 // staged buf's DMA complete
    __syncthreads();                            // reads done + staged buf ready
  }

  // ---- epilogue: activation in-register -> bf16 C-stage in LDS -> 16B stores
  float biasv[4];
#pragma unroll
  for (int fn = 0; fn < 4; ++fn) biasv[fn] = bias[n0 + wc * 64 + fn * 16 + fr];
  const int g = n0 >> 8;                        // uniform column group for this block
#pragma unroll
  for (int fm = 0; fm < 4; ++fm) {
#pragma unroll
    for (int fn = 0; fn < 4; ++fn) {
#pragma unroll
      for (int i = 0; i < 4; ++i) {
        const int row = wr * 64 + fm * 16 + fq * 4 + i;       // local row
        const int col = wc * 64 + fn * 16 + fr;               // local col
        float v = acc[fm][fn][i] + biasv[fn];
        if (MODE == 0) {
          if (g == 1 || g == 2) v = 1.0f / (1.0f + __expf(-v));
          if (g == 2) v *= node_prob[m0 + row];
        } else {
          v = fmaxf(v, 0.0f);
        }
        smem[row * 128 + (col ^ ((row & 7) << 4))] = f2bf(v);
      }
    }
  }
  __syncthreads();
  // read back: wave w owns local rows [w*32, w*32+32); lane covers 16B of a row
#pragma unroll
  for (int it = 0; it < 8; ++it) {
    const int row = w * 32 + it * 4 + fq;
    const int c8 = fr * 8;
    bf16x8 u = *(const bf16x8*)&smem[row * 128 + (c8 ^ ((row & 7) << 4))];
    if (MODE == 0) {
      *(bf16x8*)&outb[(size_t)(m0 + row) * 1024 + n0 + c8] = u;
    } else {
      bf16x8 xv = *(const bf16x8*)&x0b[(size_t)(m0 + row) * 256 + n0 + c8];
      float4 o0, o1;
      o0.x = bf2f((ushort)u[0]) + bf2f((ushort)xv[0]);
      o0.y = bf2f((ushort)u[1]) + bf2f((ushort)xv[1]);
      o0.z = bf2f((ushort)u[2]) + bf2f((ushort)xv[2]);
      o0.w = bf2f((ushort)u[3]) + bf2f((ushort)xv[3]);
      o1.x = bf2f((ushort)u[4]) + bf2f((ushort)xv[4]);
      o1.y = bf2f((ushort)u[5]) + bf2f((ushort)xv[5]);
      o1.z = bf2f((ushort)u[6]) + bf2f((ushort)xv[6]);
      o1.w = bf2f((ushort)u[7]) + bf2f((ushort)xv[7]);
      *(float4*)&outf[(size_t)(m0 + row) * 256 + n0 + c8] = o0;
      *(float4*)&outf[(size_t)(m0 + row) * 256 + n0 + c8 + 4] = o1;
    }
  }
}

// ---------------- K3: kv[b,h,d,e] = sum_n k*v ; ksum[b,h,d] = sum_n k --------
__global__ __launch_bounds__(256)
void kvred_k(const ushort* __restrict__ hqkv, float* __restrict__ kv, float* __restrict__ ksum)
{
  __shared__ ushort kt[64 * 32];
  __shared__ ushort vt[64 * 32];
  const int bh = blockIdx.x >> 5, chunk = blockIdx.x & 31;
  const int b = bh >> 3, h = bh & 7;
  const int t = threadIdx.x;
  const int d = t >> 3, e0 = (t & 7) * 4;      // thread owns (d, e0..e0+3)
  const int lrow = t >> 2, lseg = t & 3;
  float a0 = 0, a1 = 0, a2 = 0, a3 = 0, ks = 0;
  const size_t base = (size_t)b * 8192 + chunk * 256;
  for (int sub = 0; sub < 4; ++sub) {
    size_t grow = (base + sub * 64 + lrow) * 1024;
    gload_lds16(&hqkv[grow + 512 + h * 32 + lseg * 8], &kt[lrow * 32 + lseg * 8]);
    gload_lds16(&hqkv[grow + 768 + h * 32 + lseg * 8], &vt[lrow * 32 + lseg * 8]);
    vm_drain();                                 // LDS-DMA complete before publish
    __syncthreads();
#pragma unroll 8
    for (int nn = 0; nn < 64; ++nn) {
      float kd = bf2f(kt[nn * 32 + d]);
      ushort4 vv = *(const ushort4*)&vt[nn * 32 + e0];
      a0 += kd * bf2f(vv.x);
      a1 += kd * bf2f(vv.y);
      a2 += kd * bf2f(vv.z);
      a3 += kd * bf2f(vv.w);
      ks += kd;
    }
    __syncthreads();
  }
  float* kvp = &kv[(size_t)bh * 1024 + d * 32 + e0];
  atomicAdd(kvp + 0, a0);
  atomicAdd(kvp + 1, a1);
  atomicAdd(kvp + 2, a2);
  atomicAdd(kvp + 3, a3);
  if ((t & 7) == 0) atomicAdd(&ksum[bh * 32 + d], ks);
}

// ---------------- K4a: att=num/den, LN2, z = LN2(att)*(h+beta) ---------------
__global__ __launch_bounds__(256)
void attnz_k(const ushort* __restrict__ hqkv, const float* __restrict__ kv,
             const float* __restrict__ ksum, const float* __restrict__ g2,
             const float* __restrict__ b2, const float* __restrict__ beta,
             ushort* __restrict__ zb)
{
  __shared__ float kv_s[8192];                 // kv[b] : [h][d][e]
  __shared__ float ks_s[256];                  // ksum[b] : [h][d]
  __shared__ float q_s[16][256];               // q rows of this block
  const int t = threadIdx.x, l = t & 63, w = t >> 6;
  const int r0 = blockIdx.x * 16;              // 16 rows/block, all in one b
  const int b = r0 >> 13;
#pragma unroll
  for (int i = 0; i < 8; ++i)
    *(float4*)&kv_s[i * 1024 + t * 4] = *(const float4*)&kv[(size_t)b * 8192 + i * 1024 + t * 4];
  if (t < 64) *(float4*)&ks_s[t * 4] = *(const float4*)&ksum[b * 256 + t * 4];
#pragma unroll
  for (int rr = 0; rr < 4; ++rr) {             // wave w owns rows r0+w*4 .. +3
    int r = r0 + w * 4 + rr;
    ushort4 qv = *(const ushort4*)&hqkv[(size_t)r * 1024 + 256 + l * 4];
    float4 qf = {bf2f(qv.x), bf2f(qv.y), bf2f(qv.z), bf2f(qv.w)};
    *(float4*)&q_s[w * 4 + rr][l * 4] = qf;
  }
  __syncthreads();

  const int h = l >> 3, e0 = (l & 7) * 4;      // lane owns outputs j=l*4..l*4+3
  float num[4][4] = {};
  float den[4] = {0.0f, 0.0f, 0.0f, 0.0f};
#pragma unroll
  for (int dl = 0; dl < 8; ++dl) {
    const float4 ks4 = *(const float4*)&ks_s[h * 32 + dl * 4];
    float4 kvv[4];
#pragma unroll
    for (int c = 0; c < 4; ++c)
      kvv[c] = *(const float4*)&kv_s[h * 1024 + (dl * 4 + c) * 32 + e0];
#pragma unroll
    for (int rr = 0; rr < 4; ++rr) {
      const float4 q4 = *(const float4*)&q_s[w * 4 + rr][h * 32 + dl * 4];
      den[rr] += q4.x * ks4.x + q4.y * ks4.y + q4.z * ks4.z + q4.w * ks4.w;
      num[rr][0] += q4.x * kvv[0].x + q4.y * kvv[1].x + q4.z * kvv[2].x + q4.w * kvv[3].x;
      num[rr][1] += q4.x * kvv[0].y + q4.y * kvv[1].y + q4.z * kvv[2].y + q4.w * kvv[3].y;
      num[rr][2] += q4.x * kvv[0].z + q4.y * kvv[1].z + q4.z * kvv[2].z + q4.w * kvv[3].z;
      num[rr][3] += q4.x * kvv[0].w + q4.y * kvv[1].w + q4.z * kvv[2].w + q4.w * kvv[3].w;
    }
  }
  const float4 g4 = *(const float4*)&g2[l * 4];
  const float4 bb4 = *(const float4*)&b2[l * 4];
  const float4 be4 = *(const float4*)&beta[l * 4];
#pragma unroll
  for (int rr = 0; rr < 4; ++rr) {
    const int r = r0 + w * 4 + rr;
    const float inv = 1.0f / den[rr];
    float a0 = num[rr][0] * inv, a1 = num[rr][1] * inv;
    float a2 = num[rr][2] * inv, a3 = num[rr][3] * inv;
    float s = a0 + a1 + a2 + a3;
    float sq = a0 * a0 + a1 * a1 + a2 * a2 + a3 * a3;
#pragma unroll
    for (int off = 1; off < 64; off <<= 1) { s += __shfl_xor(s, off); sq += __shfl_xor(sq, off); }
    const float mean = s * (1.0f / 256.0f);
    const float var = sq * (1.0f / 256.0f) - mean * mean;
    const float rstd = rsqrtf(var + 1e-5f);
    ushort4 hv = *(const ushort4*)&hqkv[(size_t)r * 1024 + l * 4];
    ushort4 o;
    o.x = f2bf(((a0 - mean) * rstd * g4.x + bb4.x) * (bf2f(hv.x) + be4.x));
    o.y = f2bf(((a1 - mean) * rstd * g4.y + bb4.y) * (bf2f(hv.y) + be4.y));
    o.z = f2bf(((a2 - mean) * rstd * g4.z + bb4.z) * (bf2f(hv.z) + be4.z));
    o.w = f2bf(((a3 - mean) * rstd * g4.w + bb4.w) * (bf2f(hv.w) + be4.w));
    *(ushort4*)&zb[(size_t)r * 256 + l * 4] = o;
  }
}

// ---------------- host: launch -----------------------------------------------
extern "C" void kernel_launch(void* const* d_in, const int* in_sizes, int n_in,
                              void* d_out, int out_size, void* d_ws, size_t ws_size,
                              hipStream_t stream)
{
  const float* x    = (const float*)d_in[0];
  const float* np_  = (const float*)d_in[1];
  const float* Wh   = (const float*)d_in[2];
  const float* bh   = (const float*)d_in[3];
  const float* Wq   = (const float*)d_in[4];
  const float* bq   = (const float*)d_in[5];
  const float* Wk   = (const float*)d_in[6];
  const float* bk   = (const float*)d_in[7];
  const float* Wv   = (const float*)d_in[8];
  const float* bv   = (const float*)d_in[9];
  const float* Wout = (const float*)d_in[10];
  const float* bout = (const float*)d_in[11];
  const float* ln1g = (const float*)d_in[12];
  const float* ln1b = (const float*)d_in[13];
  const float* ln2g = (const float*)d_in[14];
  const float* ln2b = (const float*)d_in[15];
  const float* beta = (const float*)d_in[16];
  float* out = (float*)d_out;

  // workspace carve (~202 MB)
  uintptr_t p = (uintptr_t)d_ws;
  ushort* x0b    = (ushort*)p; p += (size_t)65536 * 256 * 2;   // 33.5 MB
  ushort* hqkv   = (ushort*)p; p += (size_t)65536 * 1024 * 2;  // 134 MB
  ushort* zb     = (ushort*)p; p += (size_t)65536 * 256 * 2;   // 33.5 MB
  ushort* Wcat_t = (ushort*)p; p += (size_t)1024 * 256 * 2;
  ushort* Woutt  = (ushort*)p; p += (size_t)256 * 256 * 2;
  float*  bcat   = (float*)p;  p += (size_t)1024 * 4;
  float*  kv     = (float*)p;  p += (size_t)65536 * 4;
  float*  ksum   = (float*)p;  p += (size_t)2048 * 4;

  prep_k<<<1548, 256, 0, stream>>>(Wh, Wq, Wk, Wv, Wout, bh, bq, bk, bv,
                                   Wcat_t, Woutt, bcat, kv, ksum);
  ln1_k<<<16384, 256, 0, stream>>>(x, ln1g, ln1b, x0b);
  gemm_bf16_k<0><<<4096, 256, 0, stream>>>(x0b, Wcat_t, bcat, np_, nullptr, hqkv, nullptr);
  kvred_k<<<2048, 256, 0, stream>>>(hqkv, kv, ksum);
  attnz_k<<<4096, 256, 0, stream>>>(hqkv, kv, ksum, ln2g, ln2b, beta, zb);
  gemm_bf16_k<1><<<1024, 256, 0, stream>>>(zb, Woutt, bout, nullptr, x0b, nullptr, out);
}